// Round 1
// baseline (290.016 us; speedup 1.0000x reference)
//
#include <hip/hip_runtime.h>

typedef unsigned short u16;
typedef __bf16 b16x8_t __attribute__((ext_vector_type(8)));
typedef unsigned short u16x8 __attribute__((ext_vector_type(8)));
typedef float f32x4 __attribute__((ext_vector_type(4)));

__device__ __forceinline__ u16 f2bf(float f) {
  union { float f; unsigned u; } x; x.f = f;
  unsigned r = x.u + 0x7fffu + ((x.u >> 16) & 1u);
  return (u16)(r >> 16);
}

__device__ __forceinline__ f32x4 mfma16(u16x8 a, u16x8 b, f32x4 c) {
  return __builtin_amdgcn_mfma_f32_16x16x32_bf16(
      __builtin_bit_cast(b16x8_t, a), __builtin_bit_cast(b16x8_t, b), c, 0, 0, 0);
}

__device__ __forceinline__ void gld_lds16(const void* g, void* l) {
  __builtin_amdgcn_global_load_lds(
      (const __attribute__((address_space(1))) void*)g,
      (__attribute__((address_space(3))) void*)l, 16, 0, 0);
}

__device__ __forceinline__ void store_out(float* p, float v) { *p = v; }
__device__ __forceinline__ void store_out(u16* p, float v) { *p = f2bf(v); }

// ---------------- elementwise f32 -> bf16 ----------------
__global__ void convert_bf16(const float* __restrict__ src, u16* __restrict__ dst, int n4) {
  int i = blockIdx.x * blockDim.x + threadIdx.x;
  if (i < n4) {
    float4 f = ((const float4*)src)[i];
    u16x8 dummy; (void)dummy;
    u16 a0 = f2bf(f.x), a1 = f2bf(f.y), a2 = f2bf(f.z), a3 = f2bf(f.w);
    unsigned lo = (unsigned)a0 | ((unsigned)a1 << 16);
    unsigned hi = (unsigned)a2 | ((unsigned)a3 << 16);
    ((uint2*)dst)[i] = make_uint2(lo, hi);
  }
}

// ---------------- f32 [R][C] -> bf16 transposed [C][R] ----------------
__global__ void transpose_f32_bf16(const float* __restrict__ src, u16* __restrict__ dst,
                                   int R, int Cn) {
  __shared__ float t[32][33];
  int c0 = blockIdx.x * 32, r0 = blockIdx.y * 32;
  int tx = threadIdx.x, ty = threadIdx.y;  // (32,8)
  for (int j = 0; j < 32; j += 8)
    t[ty + j][tx] = src[(size_t)(r0 + ty + j) * Cn + c0 + tx];
  __syncthreads();
  for (int j = 0; j < 32; j += 8)
    dst[(size_t)(c0 + ty + j) * R + r0 + tx] = f2bf(t[tx][ty + j]);
}

// ---------------- bf16 GEMM: C[M][N] = A[M][K] * Bt[N][K]^T ----------------
// 128x128 tile, BK=32, 256 threads (4 waves, 2x2), global_load_lds staging.
template <typename OutT>
__global__ __launch_bounds__(256) void gemm_bt(const u16* __restrict__ A,
                                               const u16* __restrict__ Bt,
                                               OutT* __restrict__ C,
                                               int M, int N, int K) {
  __shared__ __align__(16) u16 sA[2][128 * 32];
  __shared__ __align__(16) u16 sB[2][128 * 32];
  const int tid = threadIdx.x, lane = tid & 63, wid = tid >> 6;
  const int m0 = blockIdx.y * 128, n0 = blockIdx.x * 128;
  const int wm = (wid >> 1) * 64, wn = (wid & 1) * 64;
  f32x4 acc[4][4] = {};

  const int srow = (lane >> 2);        // 0..15 within chunk
  const int skk = (lane & 3) * 8;      // k element offset

  auto stage = [&](int buf, int kt) {
    const int k0 = kt * 32;
    for (int cc = 0; cc < 2; ++cc) {
      int c = wid * 2 + cc;
      int row = c * 16 + srow;
      gld_lds16(A + (size_t)(m0 + row) * K + k0 + skk, &sA[buf][c * 512]);
      gld_lds16(Bt + (size_t)(n0 + row) * K + k0 + skk, &sB[buf][c * 512]);
    }
  };

  const int nk = K >> 5;
  stage(0, 0);
  for (int kt = 0; kt < nk; ++kt) {
    __syncthreads();                       // staged data for buf=kt&1 visible
    if (kt + 1 < nk) stage((kt + 1) & 1, kt + 1);
    const int buf = kt & 1;
    u16x8 a[4], b[4];
#pragma unroll
    for (int i = 0; i < 4; ++i)
      a[i] = *(const u16x8*)(&sA[buf][(wm + i * 16 + (lane & 15)) * 32 + (lane >> 4) * 8]);
#pragma unroll
    for (int j = 0; j < 4; ++j)
      b[j] = *(const u16x8*)(&sB[buf][(wn + j * 16 + (lane & 15)) * 32 + (lane >> 4) * 8]);
#pragma unroll
    for (int i = 0; i < 4; ++i)
#pragma unroll
      for (int j = 0; j < 4; ++j)
        acc[i][j] = mfma16(a[i], b[j], acc[i][j]);
  }

  // epilogue: C/D layout col = lane&15, row = (lane>>4)*4 + reg
#pragma unroll
  for (int i = 0; i < 4; ++i) {
    int row = m0 + wm + i * 16 + (lane >> 4) * 4;
#pragma unroll
    for (int j = 0; j < 4; ++j) {
      int col = n0 + wn + j * 16 + (lane & 15);
#pragma unroll
      for (int r = 0; r < 4; ++r)
        store_out(&C[(size_t)(row + r) * N + col], acc[i][j][r]);
    }
  }
}

// ---------------- causal flash attention ----------------
// QKV: [8192][3072] bf16, head h: Q at col h*192, K at +64, V at +128.
// O: [8192][1024] bf16, col h*64+k.  grid (mt=8, h=16, b=8), 256 thr (4 waves).
__global__ __launch_bounds__(256) void attn_fwd(const u16* __restrict__ QKV,
                                                u16* __restrict__ O) {
  __shared__ __align__(16) u16 sK[64 * 64];
  __shared__ __align__(16) u16 sVt[64 * 64];   // [k][n] (transposed)
  __shared__ __align__(16) u16 sP[4][32 * 64];
  const int tid = threadIdx.x, lane = tid & 63, wid = tid >> 6;
  const int mt = blockIdx.x, h = blockIdx.y, bb = blockIdx.z;
  const size_t rowbase = (size_t)bb * 1024;
  const int qrow0 = mt * 128 + wid * 32;
  const int colQ = h * 192, colK = colQ + 64, colV = colQ + 128;

  // Q fragments in registers: rows qrow0 + i*16 + (lane&15), k = kb*32 + (lane>>4)*8
  u16x8 qf[2][2];
#pragma unroll
  for (int i = 0; i < 2; ++i)
#pragma unroll
    for (int kb = 0; kb < 2; ++kb) {
      size_t r = rowbase + qrow0 + i * 16 + (lane & 15);
      qf[i][kb] = *(const u16x8*)(QKV + r * 3072 + colQ + kb * 32 + (lane >> 4) * 8);
    }

  f32x4 o[2][4] = {};
  float mrow[2][4], lrow[2][4];
#pragma unroll
  for (int i = 0; i < 2; ++i)
#pragma unroll
    for (int r = 0; r < 4; ++r) { mrow[i][r] = -1e30f; lrow[i][r] = 0.f; }

  const int ntiles = 2 * mt + 2;
  for (int nt = 0; nt < ntiles; ++nt) {
    // stage K tile [64][64] linear via global_load_lds (8 chunks, 2 per wave)
    for (int cc = 0; cc < 2; ++cc) {
      int c = wid * 2 + cc;
      int n = c * 8 + (lane >> 3);
      int kk = (lane & 7) * 8;
      gld_lds16(QKV + (rowbase + nt * 64 + n) * 3072 + colK + kk, &sK[c * 512]);
    }
    // stage V transposed: sVt[k][n]
    for (int it = 0; it < 2; ++it) {
      int idx = tid + it * 256;          // 0..511
      int n = idx >> 3;                  // 0..63
      int kk = (idx & 7) * 8;
      u16x8 v = *(const u16x8*)(QKV + (rowbase + nt * 64 + n) * 3072 + colV + kk);
#pragma unroll
      for (int u = 0; u < 8; ++u) sVt[(kk + u) * 64 + n] = v[u];
    }
    __syncthreads();

    // S = Q K^T
    f32x4 s[2][4] = {};
#pragma unroll
    for (int kb = 0; kb < 2; ++kb) {
      u16x8 kf[4];
#pragma unroll
      for (int j = 0; j < 4; ++j)
        kf[j] = *(const u16x8*)(&sK[(j * 16 + (lane & 15)) * 64 + kb * 32 + (lane >> 4) * 8]);
#pragma unroll
      for (int i = 0; i < 2; ++i)
#pragma unroll
        for (int j = 0; j < 4; ++j)
          s[i][j] = mfma16(qf[i][kb], kf[j], s[i][j]);
    }

    // online softmax (rows live across 16-lane groups)
    const int n0g = nt * 64;
#pragma unroll
    for (int i = 0; i < 2; ++i) {
      int rbase = mt * 128 + wid * 32 + i * 16 + (lane >> 4) * 4;
      float tm[4];
#pragma unroll
      for (int r = 0; r < 4; ++r) tm[r] = -1e30f;
#pragma unroll
      for (int j = 0; j < 4; ++j) {
        int col = n0g + j * 16 + (lane & 15);
#pragma unroll
        for (int r = 0; r < 4; ++r) {
          float v = s[i][j][r] * 0.125f;
          if (col > rbase + r) v = -1e30f;
          s[i][j][r] = v;
          tm[r] = fmaxf(tm[r], v);
        }
      }
#pragma unroll
      for (int r = 0; r < 4; ++r) {
#pragma unroll
        for (int d = 1; d < 16; d <<= 1) tm[r] = fmaxf(tm[r], __shfl_xor(tm[r], d, 64));
        float mnew = fmaxf(mrow[i][r], tm[r]);
        float corr = __expf(mrow[i][r] - mnew);
        mrow[i][r] = mnew;
        float rs = 0.f;
#pragma unroll
        for (int j = 0; j < 4; ++j) {
          float p = __expf(s[i][j][r] - mnew);
          s[i][j][r] = p;
          rs += p;
        }
#pragma unroll
        for (int d = 1; d < 16; d <<= 1) rs += __shfl_xor(rs, d, 64);
        lrow[i][r] = lrow[i][r] * corr + rs;
#pragma unroll
        for (int j = 0; j < 4; ++j) o[i][j][r] *= corr;
      }
      // P -> LDS (per-wave buffer)
      int prow = i * 16 + (lane >> 4) * 4;
#pragma unroll
      for (int j = 0; j < 4; ++j)
#pragma unroll
        for (int r = 0; r < 4; ++r)
          sP[wid][(prow + r) * 64 + j * 16 + (lane & 15)] = f2bf(s[i][j][r]);
    }

    // O += P V
#pragma unroll
    for (int nb = 0; nb < 2; ++nb) {
      u16x8 pf[2], vf[4];
#pragma unroll
      for (int i = 0; i < 2; ++i)
        pf[i] = *(const u16x8*)(&sP[wid][(i * 16 + (lane & 15)) * 64 + nb * 32 + (lane >> 4) * 8]);
#pragma unroll
      for (int j = 0; j < 4; ++j)
        vf[j] = *(const u16x8*)(&sVt[(j * 16 + (lane & 15)) * 64 + nb * 32 + (lane >> 4) * 8]);
#pragma unroll
      for (int i = 0; i < 2; ++i)
#pragma unroll
        for (int j = 0; j < 4; ++j)
          o[i][j] = mfma16(pf[i], vf[j], o[i][j]);
    }
    __syncthreads();
  }

  // normalize + write O
#pragma unroll
  for (int i = 0; i < 2; ++i) {
    int row = mt * 128 + wid * 32 + i * 16 + (lane >> 4) * 4;
#pragma unroll
    for (int r = 0; r < 4; ++r) {
      float inv = 1.f / lrow[i][r];
#pragma unroll
      for (int j = 0; j < 4; ++j) {
        int col = h * 64 + j * 16 + (lane & 15);
        O[(rowbase + row + r) * 1024 + col] = f2bf(o[i][j][r] * inv);
      }
    }
  }
}

extern "C" void kernel_launch(void* const* d_in, const int* in_sizes, int n_in,
                              void* d_out, int out_size, void* d_ws, size_t ws_size,
                              hipStream_t stream) {
  const float* x = (const float*)d_in[0];
  const float* Pi = (const float*)d_in[1];
  const float* Po = (const float*)d_in[2];
  float* y = (float*)d_out;
  char* ws = (char*)d_ws;

  // workspace layout (bytes)
  u16* qkv  = (u16*)(ws);                     // 8192*3072*2 = 50331648
  u16* xbf  = (u16*)(ws + 50331648);          // 8192*1024*2 = 16777216
  u16* piT  = (u16*)(ws + 67108864);          // 3072*1024*2 = 6291456
  u16* poT  = (u16*)(ws + 73400320);          // 1024*1024*2 = 2097152
  u16* obuf = (u16*)(ws + 75497472);          // 8192*1024*2 = 16777216

  convert_bf16<<<8192, 256, 0, stream>>>(x, xbf, 8388608 / 4);
  dim3 tb(32, 8);
  transpose_f32_bf16<<<dim3(96, 32), tb, 0, stream>>>(Pi, piT, 1024, 3072);
  transpose_f32_bf16<<<dim3(32, 32), tb, 0, stream>>>(Po, poT, 1024, 1024);

  gemm_bt<u16><<<dim3(24, 64), 256, 0, stream>>>(xbf, piT, qkv, 8192, 3072, 1024);
  attn_fwd<<<dim3(8, 16, 8), 256, 0, stream>>>(qkv, obuf);
  gemm_bt<float><<<dim3(8, 64), 256, 0, stream>>>(obuf, poT, y, 8192, 1024, 1024);
}

// Round 2
// 184.360 us; speedup vs baseline: 1.5731x; 1.5731x over previous
//
#include <hip/hip_runtime.h>

typedef unsigned short u16;
typedef __bf16 b16x8_t __attribute__((ext_vector_type(8)));
typedef unsigned short u16x8 __attribute__((ext_vector_type(8)));
typedef float f32x4 __attribute__((ext_vector_type(4)));

__device__ __forceinline__ u16 f2bf(float f) {
  union { float f; unsigned u; } x; x.f = f;
  unsigned r = x.u + 0x7fffu + ((x.u >> 16) & 1u);
  return (u16)(r >> 16);
}

__device__ __forceinline__ f32x4 mfma16(u16x8 a, u16x8 b, f32x4 c) {
  return __builtin_amdgcn_mfma_f32_16x16x32_bf16(
      __builtin_bit_cast(b16x8_t, a), __builtin_bit_cast(b16x8_t, b), c, 0, 0, 0);
}

__device__ __forceinline__ void gld_lds16(const void* g, void* l) {
  __builtin_amdgcn_global_load_lds(
      (const __attribute__((address_space(1))) void*)g,
      (__attribute__((address_space(3))) void*)l, 16, 0, 0);
}

__device__ __forceinline__ void store_out(float* p, float v) { *p = v; }
__device__ __forceinline__ void store_out(u16* p, float v) { *p = f2bf(v); }

// ---------------- elementwise f32 -> bf16 ----------------
__global__ void convert_bf16(const float* __restrict__ src, u16* __restrict__ dst, int n4) {
  int i = blockIdx.x * blockDim.x + threadIdx.x;
  if (i < n4) {
    float4 f = ((const float4*)src)[i];
    u16 a0 = f2bf(f.x), a1 = f2bf(f.y), a2 = f2bf(f.z), a3 = f2bf(f.w);
    unsigned lo = (unsigned)a0 | ((unsigned)a1 << 16);
    unsigned hi = (unsigned)a2 | ((unsigned)a3 << 16);
    ((uint2*)dst)[i] = make_uint2(lo, hi);
  }
}

// ---------------- f32 [R][C] -> bf16 transposed [C][R] ----------------
__global__ void transpose_f32_bf16(const float* __restrict__ src, u16* __restrict__ dst,
                                   int R, int Cn) {
  __shared__ float t[32][33];
  int c0 = blockIdx.x * 32, r0 = blockIdx.y * 32;
  int tx = threadIdx.x, ty = threadIdx.y;  // (32,8)
  for (int j = 0; j < 32; j += 8)
    t[ty + j][tx] = src[(size_t)(r0 + ty + j) * Cn + c0 + tx];
  __syncthreads();
  for (int j = 0; j < 32; j += 8)
    dst[(size_t)(c0 + ty + j) * R + r0 + tx] = f2bf(t[tx][ty + j]);
}

// ---------------- V pre-transpose: qkv V-part -> Vt[(b*16+h)*64+k][n] ----------------
__global__ void transpose_v(const u16* __restrict__ QKV, u16* __restrict__ Vt) {
  __shared__ u16 t[64][72];
  const int tid = threadIdx.x;
  const int ntb = blockIdx.x, h = blockIdx.y, bb = blockIdx.z;
  const size_t rowb = (size_t)bb * 1024 + ntb * 64;
  const int colV = h * 192 + 128;
  for (int it = 0; it < 2; ++it) {
    int i2 = tid + it * 256;
    int n = i2 >> 3, kk = (i2 & 7) * 8;
    u16x8 v = *(const u16x8*)(QKV + (rowb + n) * 3072 + colV + kk);
#pragma unroll
    for (int u = 0; u < 8; ++u) t[kk + u][n] = v[u];
  }
  __syncthreads();
  const size_t vb = ((size_t)bb * 16 + h) * 64;
  for (int it = 0; it < 2; ++it) {
    int i2 = tid + it * 256;
    int k = i2 >> 3, ns = (i2 & 7) * 8;
    *(u16x8*)(Vt + (vb + k) * 1024 + ntb * 64 + ns) = *(const u16x8*)(&t[k][ns]);
  }
}

// ---------------- bf16 GEMM: C[M][N] = A[M][K] * Bt[N][K]^T ----------------
// 128x128 tile, BK=32, 256 threads (4 waves, 2x2), global_load_lds staging.
// SCALEQ: scale cols with (col%192)<64 by 0.125 (folds 1/sqrt(K) into Q).
template <typename OutT, bool SCALEQ>
__global__ __launch_bounds__(256) void gemm_bt(const u16* __restrict__ A,
                                               const u16* __restrict__ Bt,
                                               OutT* __restrict__ C,
                                               int M, int N, int K) {
  __shared__ __align__(16) u16 sA[2][128 * 32];
  __shared__ __align__(16) u16 sB[2][128 * 32];
  const int tid = threadIdx.x, lane = tid & 63, wid = tid >> 6;
  const int m0 = blockIdx.y * 128, n0 = blockIdx.x * 128;
  const int wm = (wid >> 1) * 64, wn = (wid & 1) * 64;
  f32x4 acc[4][4] = {};

  const int srow = (lane >> 2);
  const int skk = (lane & 3) * 8;

  auto stage = [&](int buf, int kt) {
    const int k0 = kt * 32;
    for (int cc = 0; cc < 2; ++cc) {
      int c = wid * 2 + cc;
      int row = c * 16 + srow;
      gld_lds16(A + (size_t)(m0 + row) * K + k0 + skk, &sA[buf][c * 512]);
      gld_lds16(Bt + (size_t)(n0 + row) * K + k0 + skk, &sB[buf][c * 512]);
    }
  };

  const int nk = K >> 5;
  stage(0, 0);
  for (int kt = 0; kt < nk; ++kt) {
    __syncthreads();
    if (kt + 1 < nk) stage((kt + 1) & 1, kt + 1);
    const int buf = kt & 1;
    u16x8 a[4], b[4];
#pragma unroll
    for (int i = 0; i < 4; ++i)
      a[i] = *(const u16x8*)(&sA[buf][(wm + i * 16 + (lane & 15)) * 32 + (lane >> 4) * 8]);
#pragma unroll
    for (int j = 0; j < 4; ++j)
      b[j] = *(const u16x8*)(&sB[buf][(wn + j * 16 + (lane & 15)) * 32 + (lane >> 4) * 8]);
#pragma unroll
    for (int i = 0; i < 4; ++i)
#pragma unroll
      for (int j = 0; j < 4; ++j)
        acc[i][j] = mfma16(a[i], b[j], acc[i][j]);
  }

#pragma unroll
  for (int i = 0; i < 4; ++i) {
    int row = m0 + wm + i * 16 + (lane >> 4) * 4;
#pragma unroll
    for (int j = 0; j < 4; ++j) {
      int col = n0 + wn + j * 16 + (lane & 15);
      float sc = 1.f;
      if (SCALEQ) { if ((col % 192) < 64) sc = 0.125f; }
#pragma unroll
      for (int r = 0; r < 4; ++r)
        store_out(&C[(size_t)(row + r) * N + col], acc[i][j][r] * sc);
    }
  }
}

// ---------------- causal flash attention v2 ----------------
// grid (z=4, h=16, b=8), 512 thr (8 waves x 16 q-rows). Block does q-tiles z and 7-z
// (equal 18 KV-iterations each). K/V double-buffered via global_load_lds with
// XOR-swizzled source; V pre-transposed globally. Q scaled by 0.125 upstream.
__global__ __launch_bounds__(512, 4) void attn_fwd2(const u16* __restrict__ QKV,
                                                    const u16* __restrict__ Vt,
                                                    u16* __restrict__ O) {
  __shared__ __align__(16) u16 sK[2][4096];
  __shared__ __align__(16) u16 sVt[2][4096];
  __shared__ __align__(16) u16 sP[8][16 * 72];
  const int tid = threadIdx.x, lane = tid & 63, wid = tid >> 6;
  const int z = blockIdx.x, h = blockIdx.y, bb = blockIdx.z;
  const size_t rowbase = (size_t)bb * 1024;
  const size_t vbase = ((size_t)bb * 16 + h) * 64;
  const int colQ = h * 192, colK = colQ + 64;
  const int hi = lane >> 4, ln = lane & 15;
  // staging geometry: chunk = wid (8 rows x 128B), dest linear, source pre-swizzled
  const int slr = lane >> 3;                  // dest row within chunk
  const int sle = ((lane & 7) ^ slr) * 8;     // swizzled source element offset
  u16* sPw = sP[wid];

  auto stageKV = [&](int buf, int nt) {
    const int n0g = nt * 64;
    gld_lds16(QKV + (rowbase + n0g + 8 * wid + slr) * 3072 + colK + sle,
              &sK[buf][wid * 512]);
    gld_lds16(Vt + (vbase + 8 * wid + slr) * 1024 + n0g + sle,
              &sVt[buf][wid * 512]);
  };

  for (int half = 0; half < 2; ++half) {
    const int mt = half ? (7 - z) : z;
    const int qrow0 = mt * 128 + wid * 16;
    const int ntiles = 2 * mt + 2;

    u16x8 qf[2];
#pragma unroll
    for (int kb = 0; kb < 2; ++kb)
      qf[kb] = *(const u16x8*)(QKV + (rowbase + qrow0 + ln) * 3072 + colQ + kb * 32 + hi * 8);

    f32x4 o[4] = {};
    float mrow[4], lrow[4];
#pragma unroll
    for (int r = 0; r < 4; ++r) { mrow[r] = -1e30f; lrow[r] = 0.f; }

    stageKV(0, 0);
    for (int nt = 0; nt < ntiles; ++nt) {
      __syncthreads();                         // drains vmcnt of stage(nt), ends nt-1 compute
      if (nt + 1 < ntiles) stageKV((nt + 1) & 1, nt + 1);
      const int buf = nt & 1;
      const int n0g = nt * 64;
      if (n0g <= qrow0 + 15) {                 // wave-uniform: skip fully-masked tiles
        // S = Q K^T  (A=Q rows, B=K rows; swizzled sK reads)
        f32x4 s[4] = {};
#pragma unroll
        for (int kb = 0; kb < 2; ++kb)
#pragma unroll
          for (int j = 0; j < 4; ++j) {
            int row = j * 16 + ln;
            int cb = (kb * 64 + hi * 16) ^ ((row & 7) << 4);
            u16x8 kfr = *(const u16x8*)(&sK[buf][(row * 128 + cb) >> 1]);
            s[j] = mfma16(qf[kb], kfr, s[j]);
          }
        // causal mask (only diagonal-touching tiles)
        if (n0g + 63 > qrow0) {
#pragma unroll
          for (int j = 0; j < 4; ++j) {
            int col = n0g + j * 16 + ln;
#pragma unroll
            for (int r = 0; r < 4; ++r)
              if (col > qrow0 + hi * 4 + r) s[j][r] = -3e38f;
          }
        }
        // online softmax (rows across 16-lane groups)
#pragma unroll
        for (int r = 0; r < 4; ++r) {
          float tm = fmaxf(fmaxf(s[0][r], s[1][r]), fmaxf(s[2][r], s[3][r]));
#pragma unroll
          for (int d = 1; d < 16; d <<= 1) tm = fmaxf(tm, __shfl_xor(tm, d, 64));
          float mnew = fmaxf(mrow[r], tm);
          float corr = __expf(mrow[r] - mnew);
          mrow[r] = mnew;
          float rs = 0.f;
#pragma unroll
          for (int j = 0; j < 4; ++j) {
            float p = __expf(s[j][r] - mnew);
            s[j][r] = p;
            rs += p;
          }
#pragma unroll
          for (int d = 1; d < 16; d <<= 1) rs += __shfl_xor(rs, d, 64);
          lrow[r] = lrow[r] * corr + rs;
#pragma unroll
          for (int dt = 0; dt < 4; ++dt) o[dt][r] *= corr;
        }
        // P -> per-wave LDS (stride 72 = 144B, b128-aligned, conflict-spread)
#pragma unroll
        for (int j = 0; j < 4; ++j)
#pragma unroll
          for (int r = 0; r < 4; ++r)
            sPw[(hi * 4 + r) * 72 + j * 16 + ln] = f2bf(s[j][r]);
        // O += P V  (A=P rows via sP, B=Vt rows via swizzled sVt)
        u16x8 pf[2];
#pragma unroll
        for (int kb2 = 0; kb2 < 2; ++kb2)
          pf[kb2] = *(const u16x8*)(&sPw[ln * 72 + kb2 * 32 + hi * 8]);
#pragma unroll
        for (int dt = 0; dt < 4; ++dt)
#pragma unroll
          for (int kb2 = 0; kb2 < 2; ++kb2) {
            int row = dt * 16 + ln;
            int cb = (kb2 * 64 + hi * 16) ^ ((row & 7) << 4);
            u16x8 vfr = *(const u16x8*)(&sVt[buf][(row * 128 + cb) >> 1]);
            o[dt] = mfma16(pf[kb2], vfr, o[dt]);
          }
      }
    }
    // write this q-tile's O
#pragma unroll
    for (int r = 0; r < 4; ++r) {
      float inv = 1.f / lrow[r];
#pragma unroll
      for (int dt = 0; dt < 4; ++dt)
        O[(rowbase + qrow0 + hi * 4 + r) * 1024 + h * 64 + dt * 16 + ln] =
            f2bf(o[dt][r] * inv);
    }
  }
}

extern "C" void kernel_launch(void* const* d_in, const int* in_sizes, int n_in,
                              void* d_out, int out_size, void* d_ws, size_t ws_size,
                              hipStream_t stream) {
  const float* x = (const float*)d_in[0];
  const float* Pi = (const float*)d_in[1];
  const float* Po = (const float*)d_in[2];
  float* y = (float*)d_out;
  char* ws = (char*)d_ws;

  // workspace layout (bytes); xbf and Vt share a slot (xbf dead after gemm1)
  u16* qkv  = (u16*)(ws);                     // 50331648
  u16* xbf  = (u16*)(ws + 50331648);          // 16777216
  u16* vt   = (u16*)(ws + 50331648);          // reuses xbf slot
  u16* piT  = (u16*)(ws + 67108864);          // 6291456
  u16* poT  = (u16*)(ws + 73400320);          // 2097152
  u16* obuf = (u16*)(ws + 75497472);          // 16777216

  convert_bf16<<<8192, 256, 0, stream>>>(x, xbf, 8388608 / 4);
  dim3 tb(32, 8);
  transpose_f32_bf16<<<dim3(96, 32), tb, 0, stream>>>(Pi, piT, 1024, 3072);
  transpose_f32_bf16<<<dim3(32, 32), tb, 0, stream>>>(Po, poT, 1024, 1024);

  gemm_bt<u16, true><<<dim3(24, 64), 256, 0, stream>>>(xbf, piT, qkv, 8192, 3072, 1024);
  transpose_v<<<dim3(16, 16, 8), 256, 0, stream>>>(qkv, vt);
  attn_fwd2<<<dim3(4, 16, 8), 512, 0, stream>>>(qkv, vt, obuf);
  gemm_bt<float, false><<<dim3(8, 64), 256, 0, stream>>>(obuf, poT, y, 8192, 1024, 1024);
}